// Round 4
// baseline (4186.699 us; speedup 1.0000x reference)
//
#include <hip/hip_runtime.h>
#include <hip/hip_bf16.h>
#include <stdint.h>

#define Tn 2048
#define Dn 1024
#define DKn 512
#define Hn 2
#define Bn 8
#define BT (Bn*Tn)   // 16384

typedef __attribute__((ext_vector_type(8))) short bf16x8;
typedef __attribute__((ext_vector_type(4))) float f32x4;
typedef __attribute__((ext_vector_type(8))) unsigned short u16x8;

__device__ inline unsigned short f2bf(float f){
  unsigned u = __float_as_uint(f);
  u += 0x7fff + ((u >> 16) & 1);
  return (unsigned short)(u >> 16);
}
__device__ inline float bf2f(unsigned short u){
  return __uint_as_float(((unsigned)u) << 16);
}

// ---------------- cast f32 -> bf16 (4 elems/thread) ----------------
__global__ __launch_bounds__(256) void cast_bf16_k(const float* __restrict__ in,
                                                   unsigned short* __restrict__ out, int n4){
  int i = blockIdx.x*256 + threadIdx.x;
  if (i >= n4) return;
  float4 f = ((const float4*)in)[i];
  ushort4 o;
  o.x = f2bf(f.x); o.y = f2bf(f.y); o.z = f2bf(f.z); o.w = f2bf(f.w);
  ((ushort4*)out)[i] = o;
}

// ---------------- bf16 NT GEMM: C[M][N] = sum_k A[m][k]*B[n][k] ----------------
// 128x128 tile, BK=64, 4 waves (2x2), 16x16x32 MFMA, global_load_lds w/ swizzled source
template<bool BF16OUT>
__global__ __launch_bounds__(256) void gemm_nt(const unsigned short* __restrict__ A,
                                               const unsigned short* __restrict__ B,
                                               void* __restrict__ Cv, int M, int N, int K){
  __shared__ unsigned short As[128*64];
  __shared__ unsigned short Bs[128*64];
  const int tid  = threadIdx.x;
  const int lane = tid & 63;
  const int wid  = tid >> 6;
  const int wm = wid >> 1, wn = wid & 1;
  const int m0 = blockIdx.y * 128, n0 = blockIdx.x * 128;

  f32x4 acc[4][4];
  #pragma unroll
  for (int m=0;m<4;m++)
    #pragma unroll
    for (int n=0;n<4;n++) acc[m][n] = (f32x4){0.f,0.f,0.f,0.f};

  const int fr_row = (lane & 15);
  const int fr_g   = (lane >> 4);

  for (int kt=0; kt<K; kt+=64){
    __syncthreads();
    #pragma unroll
    for (int i=0;i<4;i++){
      int row = i*32 + (tid >> 3);
      int col = ((tid & 7) ^ (row & 7)) << 3;   // pre-swizzled source granule
      const unsigned short* ga = A + (size_t)(m0+row)*K + kt + col;
      const unsigned short* gb = B + (size_t)(n0+row)*K + kt + col;
      __builtin_amdgcn_global_load_lds((const __attribute__((address_space(1))) uint32_t*)ga,
          (__attribute__((address_space(3))) uint32_t*)(As + i*2048 + tid*8), 16, 0, 0);
      __builtin_amdgcn_global_load_lds((const __attribute__((address_space(1))) uint32_t*)gb,
          (__attribute__((address_space(3))) uint32_t*)(Bs + i*2048 + tid*8), 16, 0, 0);
    }
    __syncthreads();
    #pragma unroll
    for (int kk=0;kk<2;kk++){
      bf16x8 af[4], bfr[4];
      #pragma unroll
      for (int m=0;m<4;m++){
        int rr = wm*64 + m*16 + fr_row;
        int gg = (kk*4 + fr_g) ^ (rr & 7);
        af[m] = *(const bf16x8*)(As + rr*64 + gg*8);
      }
      #pragma unroll
      for (int n=0;n<4;n++){
        int rr = wn*64 + n*16 + fr_row;
        int gg = (kk*4 + fr_g) ^ (rr & 7);
        bfr[n] = *(const bf16x8*)(Bs + rr*64 + gg*8);
      }
      #pragma unroll
      for (int m=0;m<4;m++)
        #pragma unroll
        for (int n=0;n<4;n++)
          acc[m][n] = __builtin_amdgcn_mfma_f32_16x16x32_bf16(af[m], bfr[n], acc[m][n], 0,0,0);
    }
  }
  const int crow = (lane >> 4) * 4;
  const int ccol = (lane & 15);
  #pragma unroll
  for (int m=0;m<4;m++)
    #pragma unroll
    for (int n=0;n<4;n++)
      #pragma unroll
      for (int r=0;r<4;r++){
        size_t idx = (size_t)(m0 + wm*64 + m*16 + crow + r)*N + (n0 + wn*64 + n*16 + ccol);
        if constexpr (BF16OUT) ((unsigned short*)Cv)[idx] = f2bf(acc[m][n][r]);
        else                   ((float*)Cv)[idx] = acc[m][n][r];
      }
}

// ---------------- per-(b,t,h) inverse k-norm from bf16 k ----------------
__global__ __launch_bounds__(256) void norm_k(const unsigned short* __restrict__ kb,
                                              float* __restrict__ invn){
  int gw = blockIdx.x*4 + (threadIdx.x >> 6);   // row id = bt*2+h, 32768 total
  int lane = threadIdx.x & 63;
  int h = gw & 1;
  size_t bt = (size_t)(gw >> 1);
  const unsigned short* kr = kb + bt*Dn + h*DKn + lane*8;
  ushort4 a = ((const ushort4*)kr)[0];
  ushort4 c = ((const ushort4*)kr)[1];
  float f0=bf2f(a.x), f1=bf2f(a.y), f2=bf2f(a.z), f3=bf2f(a.w);
  float f4=bf2f(c.x), f5=bf2f(c.y), f6=bf2f(c.z), f7=bf2f(c.w);
  float ss = f0*f0+f1*f1+f2*f2+f3*f3+f4*f4+f5*f5+f6*f6+f7*f7;
  #pragma unroll
  for (int m=1;m<64;m<<=1) ss += __shfl_xor(ss, m, 64);
  if (lane == 0) invn[gw] = 1.0f / fmaxf(sqrtf(ss), 1e-12f);
}

// ---------------- recurrence with fused gates ----------------
// grid (kkblk=8, bh=16, vh=2), 512 threads = 8 waves, pinned 2 waves/EU (256 VGPR budget).
// lane = kk within 64-col block; wave covers 32 v-elems; workgroup covers 256 v (half).
// Statically double-buffered q/v/k prefetch; float2 core for v_pk_fma_f32.
__global__ void
__attribute__((amdgpu_flat_work_group_size(512,512), amdgpu_waves_per_eu(2,2)))
recur_k(
    const float* __restrict__ q, const float* __restrict__ v,
    const unsigned short* __restrict__ kb, const float* __restrict__ invn,
    const float* __restrict__ Wg, const float* __restrict__ bg,
    const float* __restrict__ Wl, const float* __restrict__ bl,
    unsigned short* __restrict__ yp0, unsigned short* __restrict__ yp1){
  const int kkblk = blockIdx.x;
  const int bh    = blockIdx.y;
  const int vh    = blockIdx.z;
  const int b = bh >> 1, h = bh & 1;
  const int lane = threadIdx.x & 63, wid = threadIdx.x >> 6;
  const size_t rowbase = ((size_t)b * Tn) * Dn + h*DKn;
  const float* qb = q + rowbase + vh*256 + wid*32;
  const float* vb = v + rowbase + vh*256 + wid*32;
  const unsigned short* kbp = kb + rowbase + kkblk*64 + lane;
  const float* invb = invn + ((size_t)b * Tn) * Hn + h;
  unsigned short* ypx = (vh ? yp1 : yp0) + rowbase + kkblk*64;

  const int kk = kkblk*64 + lane;
  const float wg_ = Wg[h*DKn + kk], bg_ = bg[h*DKn + kk];
  const float wl_ = Wl[h*DKn + kk], bl_ = bl[h*DKn + kk];

  __shared__ float red[8][8][64];

  float2 S2[16];
  #pragma unroll
  for (int i=0;i<16;i++) S2[i] = make_float2(0.f, 0.f);

  float4 qA[8], vA[8], qB[8], vB[8];
  unsigned short kA, kB;
  float iA, iB;
  kA = kbp[0]; iA = invb[0];
  #pragma unroll
  for (int j=0;j<8;j++){ qA[j] = ((const float4*)qb)[j]; vA[j] = ((const float4*)vb)[j]; }

#define STEP(s, QC, VC, KC, IC, QN, VN, KN, IN) { \
    const int t = t0 + (s); \
    const int tnx = (t+1 < Tn) ? (t+1) : t; \
    KN = kbp[(size_t)tnx*Dn]; \
    IN = invb[(size_t)tnx*Hn]; \
    const float4* qp = (const float4*)(qb + (size_t)tnx*Dn); \
    const float4* vp = (const float4*)(vb + (size_t)tnx*Dn); \
    _Pragma("unroll") \
    for (int j=0;j<8;j++){ QN[j]=qp[j]; VN[j]=vp[j]; } \
    const float knv = bf2f(KC) * IC; \
    const float g   = 1.0f/(1.0f + __expf(-(wg_*knv + bg_))); \
    const float lm  = 1.0f/(1.0f + __expf(-(wl_*knv + bl_))); \
    const float rh  = (1.0f - lm)*g; \
    const float ch  = (1.0f - rh)*knv; \
    const float2 rh2 = make_float2(rh, rh); \
    const float2 ch2 = make_float2(ch, ch); \
    float2 y2 = make_float2(0.f, 0.f); \
    _Pragma("unroll") \
    for (int j=0;j<8;j++){ \
      float4 qc = QC[j], vc = VC[j]; \
      float2 v0 = make_float2(vc.x, vc.y), v1 = make_float2(vc.z, vc.w); \
      float2 q0 = make_float2(qc.x, qc.y), q1 = make_float2(qc.z, qc.w); \
      S2[2*j]   = rh2*S2[2*j]   + ch2*v0;  y2 = y2 + q0*S2[2*j]; \
      S2[2*j+1] = rh2*S2[2*j+1] + ch2*v1;  y2 = y2 + q1*S2[2*j+1]; \
    } \
    red[(s)][wid][lane] = y2.x + y2.y; \
  }

  for (int t0=0; t0<Tn; t0+=8){
    STEP(0, qA,vA,kA,iA, qB,vB,kB,iB)
    STEP(1, qB,vB,kB,iB, qA,vA,kA,iA)
    STEP(2, qA,vA,kA,iA, qB,vB,kB,iB)
    STEP(3, qB,vB,kB,iB, qA,vA,kA,iA)
    STEP(4, qA,vA,kA,iA, qB,vB,kB,iB)
    STEP(5, qB,vB,kB,iB, qA,vA,kA,iA)
    STEP(6, qA,vA,kA,iA, qB,vB,kB,iB)
    STEP(7, qB,vB,kB,iB, qA,vA,kA,iA)
    __syncthreads();
    {
      float sum = 0.f;
      #pragma unroll
      for (int w=0;w<8;w++) sum += red[wid][w][lane];
      ypx[(size_t)(t0+wid)*Dn + lane] = f2bf(sum);
    }
    __syncthreads();
  }
#undef STEP
}

// ---------------- combine bf16 halves -> bf16 (in-place into a) ----------------
__global__ __launch_bounds__(256) void combine_k(const u16x8* a, const u16x8* b,
                                                 u16x8* o, int n8){
  int i = blockIdx.x*256 + threadIdx.x;
  if (i >= n8) return;
  u16x8 x = a[i], y = b[i], r;
  #pragma unroll
  for (int j=0;j<8;j++) r[j] = (unsigned short)f2bf(bf2f(x[j]) + bf2f(y[j]));
  o[i] = r;
}

extern "C" void kernel_launch(void* const* d_in, const int* in_sizes, int n_in,
                              void* d_out, int out_size, void* d_ws, size_t ws_size,
                              hipStream_t stream){
  const float* x  = (const float*)d_in[0];
  const float* Wq = (const float*)d_in[1];
  const float* Wk = (const float*)d_in[2];
  const float* Wv = (const float*)d_in[3];
  const float* Wo = (const float*)d_in[4];
  const float* Wg = (const float*)d_in[5];
  const float* bg = (const float*)d_in[6];
  const float* Wl = (const float*)d_in[7];
  const float* bl = (const float*)d_in[8];
  float* out = (float*)d_out;

  // workspace layout (total 243,400,704 B = 232.1 MiB)
  const size_t NEED = 243400704ull;
  if (ws_size < NEED) return;   // diagnostic: absmax == ref absmax, no crash

  char* ws = (char*)d_ws;
  unsigned short* xb   = (unsigned short*)(ws);              // 33,554,432 B; later yp0, then y
  unsigned short* wqb  = (unsigned short*)(ws +  33554432);
  unsigned short* wkb  = (unsigned short*)(ws +  35651584);
  unsigned short* wvb  = (unsigned short*)(ws +  37748736);
  unsigned short* wob  = (unsigned short*)(ws +  39845888);
  float*          qf   = (float*)         (ws +  41943040);  // 67,108,864 B
  float*          vf   = (float*)         (ws + 109051904);  // 67,108,864 B
  unsigned short* kbuf = (unsigned short*)(ws + 176160768);  // 33,554,432 B (bf16 k)
  float*          invn = (float*)         (ws + 209715200);  // 131,072 B
  unsigned short* yp1  = (unsigned short*)(ws + 209846272);  // 33,554,432 B

  cast_bf16_k<<<16384, 256, 0, stream>>>(x,  xb,  16777216/4);
  cast_bf16_k<<<1024,  256, 0, stream>>>(Wq, wqb, 1048576/4);
  cast_bf16_k<<<1024,  256, 0, stream>>>(Wk, wkb, 1048576/4);
  cast_bf16_k<<<1024,  256, 0, stream>>>(Wv, wvb, 1048576/4);
  cast_bf16_k<<<1024,  256, 0, stream>>>(Wo, wob, 1048576/4);

  dim3 gg(8, 128);
  gemm_nt<false><<<gg, 256, 0, stream>>>(xb, wqb, qf,   BT, Dn, Dn);
  gemm_nt<false><<<gg, 256, 0, stream>>>(xb, wvb, vf,   BT, Dn, Dn);
  gemm_nt<true ><<<gg, 256, 0, stream>>>(xb, wkb, kbuf, BT, Dn, Dn);

  norm_k<<<8192, 256, 0, stream>>>(kbuf, invn);

  dim3 gr(8, 16, 2);
  recur_k<<<gr, 512, 0, stream>>>(qf, vf, kbuf, invn, Wg, bg, Wl, bl, xb /*yp0*/, yp1);

  combine_k<<<8192, 256, 0, stream>>>((const u16x8*)xb, (const u16x8*)yp1,
                                      (u16x8*)xb, 16777216/8);

  gemm_nt<false><<<gg, 256, 0, stream>>>(xb, wob, out, BT, Dn, Dn);
}

// Round 5
// 1558.859 us; speedup vs baseline: 2.6857x; 2.6857x over previous
//
#include <hip/hip_runtime.h>
#include <hip/hip_bf16.h>
#include <stdint.h>

#define Tn 2048
#define Dn 1024
#define DKn 512
#define Hn 2
#define Bn 8
#define BT (Bn*Tn)   // 16384

typedef __attribute__((ext_vector_type(8))) short bf16x8;
typedef __attribute__((ext_vector_type(4))) float f32x4;
typedef __attribute__((ext_vector_type(8))) unsigned short u16x8;

__device__ inline unsigned short f2bf(float f){
  unsigned u = __float_as_uint(f);
  u += 0x7fff + ((u >> 16) & 1);
  return (unsigned short)(u >> 16);
}
__device__ inline float bf2f(unsigned short u){
  return __uint_as_float(((unsigned)u) << 16);
}

// ---------------- cast f32 -> bf16 (4 elems/thread) ----------------
__global__ __launch_bounds__(256) void cast_bf16_k(const float* __restrict__ in,
                                                   unsigned short* __restrict__ out, int n4){
  int i = blockIdx.x*256 + threadIdx.x;
  if (i >= n4) return;
  float4 f = ((const float4*)in)[i];
  ushort4 o;
  o.x = f2bf(f.x); o.y = f2bf(f.y); o.z = f2bf(f.z); o.w = f2bf(f.w);
  ((ushort4*)out)[i] = o;
}

// ---------------- bf16 NT GEMM: C[M][N] = sum_k A[m][k]*B[n][k] ----------------
template<bool BF16OUT>
__global__ __launch_bounds__(256) void gemm_nt(const unsigned short* __restrict__ A,
                                               const unsigned short* __restrict__ B,
                                               void* __restrict__ Cv, int M, int N, int K){
  __shared__ unsigned short As[128*64];
  __shared__ unsigned short Bs[128*64];
  const int tid  = threadIdx.x;
  const int lane = tid & 63;
  const int wid  = tid >> 6;
  const int wm = wid >> 1, wn = wid & 1;
  const int m0 = blockIdx.y * 128, n0 = blockIdx.x * 128;

  f32x4 acc[4][4];
  #pragma unroll
  for (int m=0;m<4;m++)
    #pragma unroll
    for (int n=0;n<4;n++) acc[m][n] = (f32x4){0.f,0.f,0.f,0.f};

  const int fr_row = (lane & 15);
  const int fr_g   = (lane >> 4);

  for (int kt=0; kt<K; kt+=64){
    __syncthreads();
    #pragma unroll
    for (int i=0;i<4;i++){
      int row = i*32 + (tid >> 3);
      int col = ((tid & 7) ^ (row & 7)) << 3;   // pre-swizzled source granule
      const unsigned short* ga = A + (size_t)(m0+row)*K + kt + col;
      const unsigned short* gb = B + (size_t)(n0+row)*K + kt + col;
      __builtin_amdgcn_global_load_lds((const __attribute__((address_space(1))) uint32_t*)ga,
          (__attribute__((address_space(3))) uint32_t*)(As + i*2048 + tid*8), 16, 0, 0);
      __builtin_amdgcn_global_load_lds((const __attribute__((address_space(1))) uint32_t*)gb,
          (__attribute__((address_space(3))) uint32_t*)(Bs + i*2048 + tid*8), 16, 0, 0);
    }
    __syncthreads();
    #pragma unroll
    for (int kk=0;kk<2;kk++){
      bf16x8 af[4], bfr[4];
      #pragma unroll
      for (int m=0;m<4;m++){
        int rr = wm*64 + m*16 + fr_row;
        int gg = (kk*4 + fr_g) ^ (rr & 7);
        af[m] = *(const bf16x8*)(As + rr*64 + gg*8);
      }
      #pragma unroll
      for (int n=0;n<4;n++){
        int rr = wn*64 + n*16 + fr_row;
        int gg = (kk*4 + fr_g) ^ (rr & 7);
        bfr[n] = *(const bf16x8*)(Bs + rr*64 + gg*8);
      }
      #pragma unroll
      for (int m=0;m<4;m++)
        #pragma unroll
        for (int n=0;n<4;n++)
          acc[m][n] = __builtin_amdgcn_mfma_f32_16x16x32_bf16(af[m], bfr[n], acc[m][n], 0,0,0);
    }
  }
  const int crow = (lane >> 4) * 4;
  const int ccol = (lane & 15);
  #pragma unroll
  for (int m=0;m<4;m++)
    #pragma unroll
    for (int n=0;n<4;n++)
      #pragma unroll
      for (int r=0;r<4;r++){
        size_t idx = (size_t)(m0 + wm*64 + m*16 + crow + r)*N + (n0 + wn*64 + n*16 + ccol);
        if constexpr (BF16OUT) ((unsigned short*)Cv)[idx] = f2bf(acc[m][n][r]);
        else                   ((float*)Cv)[idx] = acc[m][n][r];
      }
}

// ---------------- per-(b,t,h) inverse k-norm from bf16 k ----------------
__global__ __launch_bounds__(256) void norm_k(const unsigned short* __restrict__ kb,
                                              float* __restrict__ invn){
  int gw = blockIdx.x*4 + (threadIdx.x >> 6);   // row id = bt*2+h, 32768 total
  int lane = threadIdx.x & 63;
  int h = gw & 1;
  size_t bt = (size_t)(gw >> 1);
  const unsigned short* kr = kb + bt*Dn + h*DKn + lane*8;
  ushort4 a = ((const ushort4*)kr)[0];
  ushort4 c = ((const ushort4*)kr)[1];
  float f0=bf2f(a.x), f1=bf2f(a.y), f2=bf2f(a.z), f3=bf2f(a.w);
  float f4=bf2f(c.x), f5=bf2f(c.y), f6=bf2f(c.z), f7=bf2f(c.w);
  float ss = f0*f0+f1*f1+f2*f2+f3*f3+f4*f4+f5*f5+f6*f6+f7*f7;
  #pragma unroll
  for (int m=1;m<64;m<<=1) ss += __shfl_xor(ss, m, 64);
  if (lane == 0) invn[gw] = 1.0f / fmaxf(sqrtf(ss), 1e-12f);
}

// ---------------- recurrence with fused gates, LDS-staged q/v ----------------
// 256 blocks x 512 thr (8 waves). Block = (kkblk, bh, vh) via XCD-swizzled decode.
// lane = kk within 64-col block; wave covers 32 v-elems; block covers 256 v (half).
// q/v staged in LDS (8-step tiles, double-buffered, global_load_lds) -> ~85 live VGPRs, no spill.
__global__ __launch_bounds__(512) void recur_k(
    const float* __restrict__ q, const float* __restrict__ v,
    const unsigned short* __restrict__ kb, const float* __restrict__ invn,
    const float* __restrict__ Wg, const float* __restrict__ bg,
    const float* __restrict__ Wl, const float* __restrict__ bl,
    unsigned short* __restrict__ yp0, unsigned short* __restrict__ yp1){
  // XCD swizzle: siblings (same bh,vh; kkblk 0..7) share g%8 -> same XCD L2.
  const int g    = blockIdx.x;          // 0..255
  const int xcd  = g & 7;
  const int slot = g >> 3;              // 0..31
  const int kkblk = slot & 7;
  const int pair  = slot >> 3;          // 0..3
  const int G     = xcd + 8*pair;       // 0..31 = (bh,vh) group
  const int bh    = G & 15;
  const int vh    = G >> 4;
  const int b = bh >> 1, h = bh & 1;

  const int tid  = threadIdx.x;
  const int lane = tid & 63, wid = tid >> 6;
  const size_t rowbase = ((size_t)b * Tn) * Dn + h*DKn;
  const float* qsrc = q + rowbase + vh*256;   // + t*Dn + [0..255]
  const float* vsrc = v + rowbase + vh*256;
  const unsigned short* kbp = kb + rowbase + kkblk*64 + lane;
  const float* invb = invn + ((size_t)b * Tn) * Hn + h;
  unsigned short* ypx = (vh ? yp1 : yp0) + rowbase + kkblk*64;

  const int kk = kkblk*64 + lane;
  const float wg_ = Wg[h*DKn + kk], bg_ = bg[h*DKn + kk];
  const float wl_ = Wl[h*DKn + kk], bl_ = bl[h*DKn + kk];

  __shared__ float qs_[2][8][256];
  __shared__ float vs_[2][8][256];
  __shared__ float red[8][8][64];

  // stage one 8-step tile (rows tbase..tbase+7, clamped) into parity p
  const int st_s   = tid >> 6;          // 0..7 step row
  const int st_off = (tid & 63) * 4;    // 0..252 col

#define STAGE(p, tbase) { \
    int trow = (tbase) + st_s; if (trow > Tn-1) trow = Tn-1; \
    const float* sq = qsrc + (size_t)trow*Dn + st_off; \
    const float* sv = vsrc + (size_t)trow*Dn + st_off; \
    __builtin_amdgcn_global_load_lds((const __attribute__((address_space(1))) uint32_t*)sq, \
        (__attribute__((address_space(3))) uint32_t*)(&qs_[p][0][0] + tid*4), 16, 0, 0); \
    __builtin_amdgcn_global_load_lds((const __attribute__((address_space(1))) uint32_t*)sv, \
        (__attribute__((address_space(3))) uint32_t*)(&vs_[p][0][0] + tid*4), 16, 0, 0); \
  }

  float2 S2[16];
  #pragma unroll
  for (int i=0;i<16;i++) S2[i] = make_float2(0.f, 0.f);

  unsigned short kA, kB;
  float iA, iB;
  kA = kbp[0]; iA = invb[0];

  STAGE(0, 0)
  __syncthreads();   // drain staged loads (vmcnt) + make visible

#define STEP(s, par, KC, IC, KN, IN) { \
    const int t = t0 + (s); \
    const int tnx = (t+1 < Tn) ? (t+1) : t; \
    KN = kbp[(size_t)tnx*Dn]; \
    IN = invb[(size_t)tnx*Hn]; \
    const float4* qp = (const float4*)&qs_[par][(s)][wid*32]; \
    const float4* vp = (const float4*)&vs_[par][(s)][wid*32]; \
    const float knv = bf2f(KC) * IC; \
    const float gg_  = 1.0f/(1.0f + __expf(-(wg_*knv + bg_))); \
    const float lm  = 1.0f/(1.0f + __expf(-(wl_*knv + bl_))); \
    const float rh  = (1.0f - lm)*gg_; \
    const float ch  = (1.0f - rh)*knv; \
    const float2 rh2 = make_float2(rh, rh); \
    const float2 ch2 = make_float2(ch, ch); \
    float2 y2 = make_float2(0.f, 0.f); \
    _Pragma("unroll") \
    for (int j=0;j<8;j++){ \
      float4 qc = qp[j], vc = vp[j]; \
      float2 v0 = make_float2(vc.x, vc.y), v1 = make_float2(vc.z, vc.w); \
      float2 q0 = make_float2(qc.x, qc.y), q1 = make_float2(qc.z, qc.w); \
      S2[2*j]   = rh2*S2[2*j]   + ch2*v0;  y2 = y2 + q0*S2[2*j]; \
      S2[2*j+1] = rh2*S2[2*j+1] + ch2*v1;  y2 = y2 + q1*S2[2*j+1]; \
    } \
    red[(s)][wid][lane] = y2.x + y2.y; \
  }

  int par = 0;
  for (int t0=0; t0<Tn; t0+=8){
    STAGE(par^1, t0+8)          // prefetch next tile (clamped rows on last iter)
    STEP(0, par, kA,iA, kB,iB)
    STEP(1, par, kB,iB, kA,iA)
    STEP(2, par, kA,iA, kB,iB)
    STEP(3, par, kB,iB, kA,iA)
    STEP(4, par, kA,iA, kB,iB)
    STEP(5, par, kB,iB, kA,iA)
    STEP(6, par, kA,iA, kB,iB)
    STEP(7, par, kB,iB, kA,iA)
    __syncthreads();            // red visible + next-tile staging drained
    {
      float sum = 0.f;
      #pragma unroll
      for (int w=0;w<8;w++) sum += red[wid][w][lane];
      ypx[(size_t)(t0+wid)*Dn + lane] = f2bf(sum);
    }
    __syncthreads();            // protect red reuse
    par ^= 1;
  }
#undef STEP
#undef STAGE
}

// ---------------- combine bf16 halves -> bf16 (in-place into a) ----------------
__global__ __launch_bounds__(256) void combine_k(const u16x8* a, const u16x8* b,
                                                 u16x8* o, int n8){
  int i = blockIdx.x*256 + threadIdx.x;
  if (i >= n8) return;
  u16x8 x = a[i], y = b[i], r;
  #pragma unroll
  for (int j=0;j<8;j++) r[j] = (unsigned short)f2bf(bf2f(x[j]) + bf2f(y[j]));
  o[i] = r;
}

extern "C" void kernel_launch(void* const* d_in, const int* in_sizes, int n_in,
                              void* d_out, int out_size, void* d_ws, size_t ws_size,
                              hipStream_t stream){
  const float* x  = (const float*)d_in[0];
  const float* Wq = (const float*)d_in[1];
  const float* Wk = (const float*)d_in[2];
  const float* Wv = (const float*)d_in[3];
  const float* Wo = (const float*)d_in[4];
  const float* Wg = (const float*)d_in[5];
  const float* bg = (const float*)d_in[6];
  const float* Wl = (const float*)d_in[7];
  const float* bl = (const float*)d_in[8];
  float* out = (float*)d_out;

  // workspace layout (total 243,400,704 B = 232.1 MiB)
  const size_t NEED = 243400704ull;
  if (ws_size < NEED) return;   // diagnostic: absmax == ref absmax, no crash

  char* ws = (char*)d_ws;
  unsigned short* xb   = (unsigned short*)(ws);              // 33,554,432 B; later yp0, then y
  unsigned short* wqb  = (unsigned short*)(ws +  33554432);
  unsigned short* wkb  = (unsigned short*)(ws +  35651584);
  unsigned short* wvb  = (unsigned short*)(ws +  37748736);
  unsigned short* wob  = (unsigned short*)(ws +  39845888);
  float*          qf   = (float*)         (ws +  41943040);  // 67,108,864 B
  float*          vf   = (float*)         (ws + 109051904);  // 67,108,864 B
  unsigned short* kbuf = (unsigned short*)(ws + 176160768);  // 33,554,432 B (bf16 k)
  float*          invn = (float*)         (ws + 209715200);  // 131,072 B
  unsigned short* yp1  = (unsigned short*)(ws + 209846272);  // 33,554,432 B

  cast_bf16_k<<<16384, 256, 0, stream>>>(x,  xb,  16777216/4);
  cast_bf16_k<<<1024,  256, 0, stream>>>(Wq, wqb, 1048576/4);
  cast_bf16_k<<<1024,  256, 0, stream>>>(Wk, wkb, 1048576/4);
  cast_bf16_k<<<1024,  256, 0, stream>>>(Wv, wvb, 1048576/4);
  cast_bf16_k<<<1024,  256, 0, stream>>>(Wo, wob, 1048576/4);

  dim3 gg(8, 128);
  gemm_nt<false><<<gg, 256, 0, stream>>>(xb, wqb, qf,   BT, Dn, Dn);
  gemm_nt<false><<<gg, 256, 0, stream>>>(xb, wvb, vf,   BT, Dn, Dn);
  gemm_nt<true ><<<gg, 256, 0, stream>>>(xb, wkb, kbuf, BT, Dn, Dn);

  norm_k<<<8192, 256, 0, stream>>>(kbuf, invn);

  recur_k<<<256, 512, 0, stream>>>(qf, vf, kbuf, invn, Wg, bg, Wl, bl, xb /*yp0*/, yp1);

  combine_k<<<8192, 256, 0, stream>>>((const u16x8*)xb, (const u16x8*)yp1,
                                      (u16x8*)xb, 16777216/8);

  gemm_nt<false><<<gg, 256, 0, stream>>>(xb, wob, out, BT, Dn, Dn);
}